// Round 7
// baseline (132.117 us; speedup 1.0000x reference)
//
#include <hip/hip_runtime.h>
#include <stdint.h>

#define B_  4096
#define F_  512
#define T_  2048
#define D_  4
#define M_  (T_ * D_)   // 8192 GEMM-M (trees*dims)
#define KC_ (F_ / 8)    // 64 16-byte k-chunks per row
#define TAU 0.2018004745467103f

typedef __attribute__((ext_vector_type(8)))  short bf16x8;
typedef __attribute__((ext_vector_type(16))) float f32x16;

static __device__ __forceinline__ unsigned short f2bf(float f) {
  union { float f; uint32_t u; } v; v.f = f;
  uint32_t r = v.u + 0x7fffu + ((v.u >> 16) & 1u);  // RNE
  return (unsigned short)(r >> 16);
}

// ---------------------------------------------------------------------------
// Prep (single launch, two jobs by blockIdx):
//  blocks [0,1024):      x (B,F) fp32 -> xbF frag-major bf16: cell(kc,n)=16B
//  blocks [1024,3072):   softmax rows of feature_logits -> wbF frag-major
// ---------------------------------------------------------------------------
__global__ __launch_bounds__(256) void prep(
    const float* __restrict__ x, const float* __restrict__ logits,
    unsigned short* __restrict__ xbF, unsigned short* __restrict__ wbF) {
  if (blockIdx.x < 1024) {
    int w = blockIdx.x * 4 + (threadIdx.x >> 6);
    int l = threadIdx.x & 63;
    int n  = ((w & 511) << 3) + (l >> 3);
    int kc = ((w >> 9) << 3) + (l & 7);
    const float4* p = (const float4*)(x + (size_t)n * F_ + kc * 8);
    float4 a = p[0], b = p[1];
    bf16x8 o;
    o[0] = (short)f2bf(a.x); o[1] = (short)f2bf(a.y);
    o[2] = (short)f2bf(a.z); o[3] = (short)f2bf(a.w);
    o[4] = (short)f2bf(b.x); o[5] = (short)f2bf(b.y);
    o[6] = (short)f2bf(b.z); o[7] = (short)f2bf(b.w);
    *(bf16x8*)(xbF + ((size_t)kc * B_ + n) * 8) = o;
  } else {
    __shared__ uint32_t ls[4 * 257];
    int bj = blockIdx.x - 1024;
    int wv = threadIdx.x >> 6, l = threadIdx.x & 63;
    int m  = bj * 4 + wv;
    const float* src = logits + (size_t)m * F_ + l * 8;
    float4 v0 = *(const float4*)src;
    float4 v1 = *(const float4*)(src + 4);
    float mx = fmaxf(fmaxf(fmaxf(v0.x, v0.y), fmaxf(v0.z, v0.w)),
                     fmaxf(fmaxf(v1.x, v1.y), fmaxf(v1.z, v1.w)));
    #pragma unroll
    for (int s = 32; s >= 1; s >>= 1) mx = fmaxf(mx, __shfl_xor(mx, s, 64));
    float e[8];
    e[0] = __expf(v0.x - mx); e[1] = __expf(v0.y - mx);
    e[2] = __expf(v0.z - mx); e[3] = __expf(v0.w - mx);
    e[4] = __expf(v1.x - mx); e[5] = __expf(v1.y - mx);
    e[6] = __expf(v1.z - mx); e[7] = __expf(v1.w - mx);
    float sm = e[0] + e[1] + e[2] + e[3] + e[4] + e[5] + e[6] + e[7];
    #pragma unroll
    for (int s = 32; s >= 1; s >>= 1) sm += __shfl_xor(sm, s, 64);
    float inv = 1.0f / sm;
    union { bf16x8 v; uint32_t u[4]; } cv;
    #pragma unroll
    for (int i = 0; i < 8; i++) cv.v[i] = (short)f2bf(e[i] * inv);
    #pragma unroll
    for (int j = 0; j < 4; j++) ls[wv * 257 + l * 4 + j] = cv.u[j];
    __syncthreads();
    int kc = threadIdx.x >> 2, mm = threadIdx.x & 3;
    union { uint32_t u[4]; bf16x8 v; } rv;
    #pragma unroll
    for (int j = 0; j < 4; j++) rv.u[j] = ls[mm * 257 + kc * 4 + j];
    *(bf16x8*)(wbF + ((size_t)kc * M_ + bj * 4 + mm) * 8) = rv.v;
  }
}

// ---------------------------------------------------------------------------
// Barrier-free MFMA GEMM, occupancy-first: 64x64 wave tile (2x2 of
// v_mfma_f32_32x32x16_bf16, 64 AGPR acc) -> 3-4 waves/SIMD so TLP covers
// the ~250cyc L2 frag-load latency (3x128 cyc MFMA issue per window).
// Block 128m x 128n, 4 waves 2x2. Both operands frag-major global
// (coalesced dwordx4 per fragment), register ring distance 2, no K-loop
// barriers. C-layout/lane: n=lane&31, d=reg&3, tree=2*(reg>>2)+(lane>>5).
// Grid: x = m-blocks fast -> consecutive blocks share the B strip (L2).
// ---------------------------------------------------------------------------
__global__ __launch_bounds__(256, 3) void odst_mfma(
    const unsigned short* __restrict__ wbF,  // frag-major [KC][M] 16B cells
    const unsigned short* __restrict__ xbF,  // frag-major [KC][B] 16B cells
    const float* __restrict__ thr,           // [T][4]
    const float* __restrict__ leaf,          // [T][16]
    float* __restrict__ out) {               // [B][T]
  __shared__ float eb[128 * 34];             // 17408 B epilogue staging

  const int tid  = threadIdx.x;
  const int lane = tid & 63, wid = tid >> 6;
  const int wm = wid >> 1, wn = wid & 1;
  const int m0 = blockIdx.x * 128;           // m-blocks on x (fast)
  const int n0 = blockIdx.y * 128;
  const int col = lane & 31, hi = lane >> 5;

  const unsigned short* ap[2];
  #pragma unroll
  for (int i = 0; i < 2; i++)
    ap[i] = wbF + (size_t)hi * (M_ * 8) +
            (size_t)(m0 + wm * 64 + i * 32 + col) * 8;
  const unsigned short* bp[2];
  #pragma unroll
  for (int j = 0; j < 2; j++)
    bp[j] = xbF + (size_t)hi * (B_ * 8) +
            (size_t)(n0 + wn * 64 + j * 32 + col) * 8;

  f32x16 acc[2][2] = {};
  bf16x8 ar[3][2], br[3][2];

#define LOAD_SLOT(s, r) do {                                   \
    size_t ka = (size_t)(2 * (s)) * (M_ * 8);                  \
    size_t kb = (size_t)(2 * (s)) * (B_ * 8);                  \
    ar[r][0] = *(const bf16x8*)(ap[0] + ka);                   \
    ar[r][1] = *(const bf16x8*)(ap[1] + ka);                   \
    br[r][0] = *(const bf16x8*)(bp[0] + kb);                   \
    br[r][1] = *(const bf16x8*)(bp[1] + kb);                   \
  } while (0)

  LOAD_SLOT(0, 0);
  LOAD_SLOT(1, 1);
  #pragma unroll
  for (int s = 0; s < 32; s++) {
    if (s + 2 < 32) LOAD_SLOT(s + 2, (s + 2) % 3);
    const int r = s % 3;
    #pragma unroll
    for (int i = 0; i < 2; i++)
      #pragma unroll
      for (int j = 0; j < 2; j++)
        acc[i][j] = __builtin_amdgcn_mfma_f32_32x32x16_bf16(
            ar[r][i], br[r][j], acc[i][j], 0, 0, 0);
  }
#undef LOAD_SLOT

  // ---- fused epilogue (in-register sigmoid/leaf), stage via LDS ----
  const float inv_tau = 1.0f / TAU;
  const int t0 = m0 >> 2;
  #pragma unroll
  for (int i = 0; i < 2; i++) {
    #pragma unroll
    for (int g = 0; g < 4; g++) {
      int tl = wm * 16 + i * 8 + 2 * g + hi;          // tree within block [0,32)
      int t  = t0 + tl;
      float4 th  = *(const float4*)(thr + t * 4);
      float4 lf0 = *(const float4*)(leaf + t * 16);
      float4 lf1 = *(const float4*)(leaf + t * 16 + 4);
      float4 lf2 = *(const float4*)(leaf + t * 16 + 8);
      float4 lf3 = *(const float4*)(leaf + t * 16 + 12);
      float c2x = th.x * inv_tau, c2y = th.y * inv_tau,
            c2z = th.z * inv_tau, c2w = th.w * inv_tau;
      #pragma unroll
      for (int j = 0; j < 2; j++) {
        float p0 = __builtin_amdgcn_rcpf(1.0f + __expf(fmaf(acc[i][j][g * 4 + 0], -inv_tau, c2x)));
        float p1 = __builtin_amdgcn_rcpf(1.0f + __expf(fmaf(acc[i][j][g * 4 + 1], -inv_tau, c2y)));
        float p2 = __builtin_amdgcn_rcpf(1.0f + __expf(fmaf(acc[i][j][g * 4 + 2], -inv_tau, c2z)));
        float p3 = __builtin_amdgcn_rcpf(1.0f + __expf(fmaf(acc[i][j][g * 4 + 3], -inv_tau, c2w)));
        float q0 = 1.0f - p0, q1 = 1.0f - p1, q2 = 1.0f - p2, q3 = 1.0f - p3;
        float A0 = lf0.x * q0 + lf0.y * p0;
        float A1 = lf0.z * q0 + lf0.w * p0;
        float A2 = lf1.x * q0 + lf1.y * p0;
        float A3 = lf1.z * q0 + lf1.w * p0;
        float A4 = lf2.x * q0 + lf2.y * p0;
        float A5 = lf2.z * q0 + lf2.w * p0;
        float A6 = lf3.x * q0 + lf3.y * p0;
        float A7 = lf3.z * q0 + lf3.w * p0;
        float B0 = A0 * q1 + A1 * p1;
        float B1 = A2 * q1 + A3 * p1;
        float B2 = A4 * q1 + A5 * p1;
        float B3 = A6 * q1 + A7 * p1;
        float C0 = B0 * q2 + B1 * p2;
        float C1 = B2 * q2 + B3 * p2;
        float o  = C0 * q3 + C1 * p3;
        int bl = wn * 64 + j * 32 + col;               // batch within block
        eb[bl * 34 + tl] = o;                          // stride 34: 2-way (free)
      }
    }
  }
  __syncthreads();

  // coalesced store: 128 batch rows x 32 trees, float4 per thread-slot
  #pragma unroll
  for (int q = 0; q < 4; q++) {
    int row = q * 32 + (tid >> 3);
    int s   = tid & 7;
    float4 v = *(const float4*)(eb + row * 34 + s * 4);
    *(float4*)(out + (size_t)(n0 + row) * T_ + t0 + s * 4) = v;
  }
}

extern "C" void kernel_launch(void* const* d_in, const int* in_sizes, int n_in,
                              void* d_out, int out_size, void* d_ws, size_t ws_size,
                              hipStream_t stream) {
  const float* x    = (const float*)d_in[0];  // (B, F)
  const float* fl   = (const float*)d_in[1];  // (T, D, F)
  const float* thr  = (const float*)d_in[2];  // (T, D)
  const float* leaf = (const float*)d_in[3];  // (T, 16)
  float* out = (float*)d_out;                 // (B, T)

  unsigned short* wbF = (unsigned short*)d_ws;                                  // 8 MB
  unsigned short* xbF = (unsigned short*)((char*)d_ws + (size_t)KC_ * M_ * 16); // 4 MB

  prep<<<dim3(1024 + M_ / 4), dim3(256), 0, stream>>>(x, fl, xbF, wbF);
  odst_mfma<<<dim3(M_ / 128, B_ / 128), dim3(256), 0, stream>>>(wbF, xbF, thr, leaf, out);
}

// Round 8
// 128.161 us; speedup vs baseline: 1.0309x; 1.0309x over previous
//
#include <hip/hip_runtime.h>
#include <stdint.h>

#define B_  4096
#define F_  512
#define T_  2048
#define D_  4
#define M_  (T_ * D_)   // 8192 GEMM-M (trees*dims)
#define KC_ (F_ / 8)    // 64 16-byte k-chunks per row
#define TAU 0.2018004745467103f

typedef __attribute__((ext_vector_type(8)))  short bf16x8;
typedef __attribute__((ext_vector_type(16))) float f32x16;

static __device__ __forceinline__ unsigned short f2bf(float f) {
  union { float f; uint32_t u; } v; v.f = f;
  uint32_t r = v.u + 0x7fffu + ((v.u >> 16) & 1u);  // RNE
  return (unsigned short)(r >> 16);
}

// ---------------------------------------------------------------------------
// Prep (single launch, two jobs by blockIdx):
//  blocks [0,1024):      x (B,F) fp32 -> xbF frag-major bf16: cell(kc,n)=16B
//  blocks [1024,3072):   softmax rows of feature_logits -> wbF frag-major
// ---------------------------------------------------------------------------
__global__ __launch_bounds__(256) void prep(
    const float* __restrict__ x, const float* __restrict__ logits,
    unsigned short* __restrict__ xbF, unsigned short* __restrict__ wbF) {
  if (blockIdx.x < 1024) {
    int w = blockIdx.x * 4 + (threadIdx.x >> 6);
    int l = threadIdx.x & 63;
    int n  = ((w & 511) << 3) + (l >> 3);
    int kc = ((w >> 9) << 3) + (l & 7);
    const float4* p = (const float4*)(x + (size_t)n * F_ + kc * 8);
    float4 a = p[0], b = p[1];
    bf16x8 o;
    o[0] = (short)f2bf(a.x); o[1] = (short)f2bf(a.y);
    o[2] = (short)f2bf(a.z); o[3] = (short)f2bf(a.w);
    o[4] = (short)f2bf(b.x); o[5] = (short)f2bf(b.y);
    o[6] = (short)f2bf(b.z); o[7] = (short)f2bf(b.w);
    *(bf16x8*)(xbF + ((size_t)kc * B_ + n) * 8) = o;
  } else {
    __shared__ uint32_t ls[4 * 257];
    int bj = blockIdx.x - 1024;
    int wv = threadIdx.x >> 6, l = threadIdx.x & 63;
    int m  = bj * 4 + wv;
    const float* src = logits + (size_t)m * F_ + l * 8;
    float4 v0 = *(const float4*)src;
    float4 v1 = *(const float4*)(src + 4);
    float mx = fmaxf(fmaxf(fmaxf(v0.x, v0.y), fmaxf(v0.z, v0.w)),
                     fmaxf(fmaxf(v1.x, v1.y), fmaxf(v1.z, v1.w)));
    #pragma unroll
    for (int s = 32; s >= 1; s >>= 1) mx = fmaxf(mx, __shfl_xor(mx, s, 64));
    float e[8];
    e[0] = __expf(v0.x - mx); e[1] = __expf(v0.y - mx);
    e[2] = __expf(v0.z - mx); e[3] = __expf(v0.w - mx);
    e[4] = __expf(v1.x - mx); e[5] = __expf(v1.y - mx);
    e[6] = __expf(v1.z - mx); e[7] = __expf(v1.w - mx);
    float sm = e[0] + e[1] + e[2] + e[3] + e[4] + e[5] + e[6] + e[7];
    #pragma unroll
    for (int s = 32; s >= 1; s >>= 1) sm += __shfl_xor(sm, s, 64);
    float inv = 1.0f / sm;
    union { bf16x8 v; uint32_t u[4]; } cv;
    #pragma unroll
    for (int i = 0; i < 8; i++) cv.v[i] = (short)f2bf(e[i] * inv);
    #pragma unroll
    for (int j = 0; j < 4; j++) ls[wv * 257 + l * 4 + j] = cv.u[j];
    __syncthreads();
    int kc = threadIdx.x >> 2, mm = threadIdx.x & 3;
    union { uint32_t u[4]; bf16x8 v; } rv;
    #pragma unroll
    for (int j = 0; j < 4; j++) rv.u[j] = ls[mm * 257 + kc * 4 + j];
    *(bf16x8*)(wbF + ((size_t)kc * M_ + bj * 4 + mm) * 8) = rv.v;
  }
}

// ---------------------------------------------------------------------------
// LDS-delivery MFMA GEMM, occupancy-first: 128x128 tile, BK=64, SINGLE
// 32KB buffer (As 16KB + Bs 16KB; epilogue aliases it) -> 4 blocks/CU.
// Barrier drains of one block overlap the other 3 blocks' MFMA/ds_read.
// LDS layout [kc][row] cells of 16B: staging from frag-major global is
// perfectly coalesced (lane = consecutive row), and b128 frag reads are
// conflict-free per 8-lane phase (row varies across lanes).
// 4 waves 2x2, wave tile 64x64 = 2x2 of v_mfma_f32_32x32x16_bf16 per K=16.
// C-layout/lane: n=lane&31, d=reg&3, tree=2*(reg>>2)+(lane>>5).
// Grid: x = m-blocks fast -> consecutive blocks share the B strip (L2).
// ---------------------------------------------------------------------------
__global__ __launch_bounds__(256, 4) void odst_mfma(
    const unsigned short* __restrict__ wbF,  // frag-major [KC][M] 16B cells
    const unsigned short* __restrict__ xbF,  // frag-major [KC][B] 16B cells
    const float* __restrict__ thr,           // [T][4]
    const float* __restrict__ leaf,          // [T][16]
    float* __restrict__ out) {               // [B][T]
  __shared__ __align__(16) char smem[32768];
  unsigned short* As = (unsigned short*)smem;            // [8 kc][128 row] cells
  unsigned short* Bs = (unsigned short*)(smem + 16384);  // [8 kc][128 row] cells
  float* eb = (float*)smem;                              // aliased: [128][34]

  const int tid  = threadIdx.x;
  const int lane = tid & 63, wid = tid >> 6;
  const int wm = wid >> 1, wn = wid & 1;
  const int m0 = blockIdx.x * 128;           // m-blocks on x (fast)
  const int n0 = blockIdx.y * 128;
  const int col = lane & 31, hi = lane >> 5;

  f32x16 acc[2][2] = {};

  for (int it = 0; it < 8; it++) {
    __syncthreads();                         // protect As/Bs overwrite
    const int kc0 = it * 8;
    #pragma unroll
    for (int q = 0; q < 4; q++) {
      int sbase = q * 256 + wid * 64;        // wave-uniform slot base
      int slot  = sbase + lane;
      int kcp = slot >> 7, row = slot & 127;
      const unsigned short* srcA =
          wbF + ((size_t)(kc0 + kcp) * M_ + m0 + row) * 8;
      const unsigned short* srcB =
          xbF + ((size_t)(kc0 + kcp) * B_ + n0 + row) * 8;
      __builtin_amdgcn_global_load_lds(
          (const __attribute__((address_space(1))) uint32_t*)srcA,
          (__attribute__((address_space(3))) uint32_t*)(As + (size_t)sbase * 8),
          16, 0, 0);
      __builtin_amdgcn_global_load_lds(
          (const __attribute__((address_space(1))) uint32_t*)srcB,
          (__attribute__((address_space(3))) uint32_t*)(Bs + (size_t)sbase * 8),
          16, 0, 0);
    }
    __syncthreads();                         // drain stage

    #pragma unroll
    for (int s = 0; s < 4; s++) {
      const int kk = (2 * s + hi) << 7;      // kc slot * 128 cells
      bf16x8 a[2], b[2];
      a[0] = *(const bf16x8*)(As + (size_t)(kk + wm * 64 + col) * 8);
      a[1] = *(const bf16x8*)(As + (size_t)(kk + wm * 64 + 32 + col) * 8);
      b[0] = *(const bf16x8*)(Bs + (size_t)(kk + wn * 64 + col) * 8);
      b[1] = *(const bf16x8*)(Bs + (size_t)(kk + wn * 64 + 32 + col) * 8);
      #pragma unroll
      for (int i = 0; i < 2; i++)
        #pragma unroll
        for (int j = 0; j < 2; j++)
          acc[i][j] = __builtin_amdgcn_mfma_f32_32x32x16_bf16(
              a[i], b[j], acc[i][j], 0, 0, 0);
    }
  }

  __syncthreads();  // all frag reads done before eb overwrites As/Bs

  // ---- fused epilogue (in-register sigmoid/leaf), stage via LDS ----
  const float inv_tau = 1.0f / TAU;
  const int t0 = m0 >> 2;
  #pragma unroll
  for (int i = 0; i < 2; i++) {
    #pragma unroll
    for (int g = 0; g < 4; g++) {
      int tl = wm * 16 + i * 8 + 2 * g + hi;          // tree within block [0,32)
      int t  = t0 + tl;
      float4 th  = *(const float4*)(thr + t * 4);
      float4 lf0 = *(const float4*)(leaf + t * 16);
      float4 lf1 = *(const float4*)(leaf + t * 16 + 4);
      float4 lf2 = *(const float4*)(leaf + t * 16 + 8);
      float4 lf3 = *(const float4*)(leaf + t * 16 + 12);
      float c2x = th.x * inv_tau, c2y = th.y * inv_tau,
            c2z = th.z * inv_tau, c2w = th.w * inv_tau;
      #pragma unroll
      for (int j = 0; j < 2; j++) {
        float p0 = __builtin_amdgcn_rcpf(1.0f + __expf(fmaf(acc[i][j][g * 4 + 0], -inv_tau, c2x)));
        float p1 = __builtin_amdgcn_rcpf(1.0f + __expf(fmaf(acc[i][j][g * 4 + 1], -inv_tau, c2y)));
        float p2 = __builtin_amdgcn_rcpf(1.0f + __expf(fmaf(acc[i][j][g * 4 + 2], -inv_tau, c2z)));
        float p3 = __builtin_amdgcn_rcpf(1.0f + __expf(fmaf(acc[i][j][g * 4 + 3], -inv_tau, c2w)));
        float q0 = 1.0f - p0, q1 = 1.0f - p1, q2 = 1.0f - p2, q3 = 1.0f - p3;
        float A0 = lf0.x * q0 + lf0.y * p0;
        float A1 = lf0.z * q0 + lf0.w * p0;
        float A2 = lf1.x * q0 + lf1.y * p0;
        float A3 = lf1.z * q0 + lf1.w * p0;
        float A4 = lf2.x * q0 + lf2.y * p0;
        float A5 = lf2.z * q0 + lf2.w * p0;
        float A6 = lf3.x * q0 + lf3.y * p0;
        float A7 = lf3.z * q0 + lf3.w * p0;
        float B0 = A0 * q1 + A1 * p1;
        float B1 = A2 * q1 + A3 * p1;
        float B2 = A4 * q1 + A5 * p1;
        float B3 = A6 * q1 + A7 * p1;
        float C0 = B0 * q2 + B1 * p2;
        float C1 = B2 * q2 + B3 * p2;
        float o  = C0 * q3 + C1 * p3;
        int bl = wn * 64 + j * 32 + col;               // batch within block
        eb[bl * 34 + tl] = o;                          // stride 34: 2-way (free)
      }
    }
  }
  __syncthreads();

  // coalesced store: 128 batch rows x 32 trees, float4 per thread-slot
  #pragma unroll
  for (int q = 0; q < 4; q++) {
    int row = q * 32 + (tid >> 3);
    int s   = tid & 7;
    float4 v = *(const float4*)(eb + row * 34 + s * 4);
    *(float4*)(out + (size_t)(n0 + row) * T_ + t0 + s * 4) = v;
  }
}

extern "C" void kernel_launch(void* const* d_in, const int* in_sizes, int n_in,
                              void* d_out, int out_size, void* d_ws, size_t ws_size,
                              hipStream_t stream) {
  const float* x    = (const float*)d_in[0];  // (B, F)
  const float* fl   = (const float*)d_in[1];  // (T, D, F)
  const float* thr  = (const float*)d_in[2];  // (T, D)
  const float* leaf = (const float*)d_in[3];  // (T, 16)
  float* out = (float*)d_out;                 // (B, T)

  unsigned short* wbF = (unsigned short*)d_ws;                                  // 8 MB
  unsigned short* xbF = (unsigned short*)((char*)d_ws + (size_t)KC_ * M_ * 16); // 4 MB

  prep<<<dim3(1024 + M_ / 4), dim3(256), 0, stream>>>(x, fl, xbF, wbF);
  odst_mfma<<<dim3(M_ / 128, B_ / 128), dim3(256), 0, stream>>>(wbF, xbF, thr, leaf, out);
}